// Round 17
// baseline (3304.833 us; speedup 1.0000x reference)
//
#include <hip/hip_runtime.h>
#include <hip/hip_bf16.h>
#include <stdint.h>
#include <math.h>

typedef __hip_bfloat16 bf16;
typedef short s16x8 __attribute__((ext_vector_type(8)));
typedef short s16x4 __attribute__((ext_vector_type(4)));
typedef float f32x4 __attribute__((ext_vector_type(4)));

#define SCALE_QK 0.03608439182435161f   /* 768^-0.5 (ref scales by n_embd^-0.5) */
#define NEG_BIG  -1.0e30f

// ---------------------------------------------------------------------------
// async global->LDS, 16B per lane (verified r4/r5/r7).
// ---------------------------------------------------------------------------
__device__ __forceinline__ void lds_dma16(void* lds_uniform, const void* gsrc) {
  __builtin_amdgcn_global_load_lds(
      (const __attribute__((address_space(1))) unsigned int*)(uintptr_t)gsrc,
      (__attribute__((address_space(3))) unsigned int*)(unsigned int)(uintptr_t)lds_uniform,
      16, 0, 0);
}

enum { EPI_BF16 = 0, EPI_GELU = 1, EPI_RES = 2, EPI_HEAD = 3 };

// ===========================================================================
// GEMM 64x128 (4 waves, dbuf, src-perm swizzle) — verified r13/r14/r16.
// proj/mlp2 (N=768). (r15 lesson: split-K atomics regressed — reverted.)
// ===========================================================================
template <int EPI>
__global__ __launch_bounds__(256)
void gemm_bt64(const bf16* __restrict__ A, const bf16* __restrict__ BT,
               const float* __restrict__ bias, float* Cf, bf16* Cb,
               int M, int N, int K, int Nreal)
{
  __shared__ __align__(16) bf16 As[2][64 * 32];
  __shared__ __align__(16) bf16 Bs[2][128 * 32];
  const int tid = threadIdx.x;
  const int w = tid >> 6, l = tid & 63;
  const int lo = l & 15, hi = l >> 4;
  const long row0 = (long)blockIdx.y * 64;
  const long col0 = (long)blockIdx.x * 128;

  const int c0 = w * 64 + l, c1 = c0 + 256;
  const int s0 = ((c0 & 3) ^ ((c0 >> 2) & 3)) * 8;
  const int s1 = ((c1 & 3) ^ ((c1 >> 2) & 3)) * 8;
  const bf16* a0 = A + (row0 + (c0 >> 2)) * K + s0;
  const bf16* b0 = BT + (col0 + (c0 >> 2)) * K + s0;
  const bf16* b1 = BT + (col0 + (c1 >> 2)) * K + s1;
  const int w512 = w * 512;

  const f32x4 zero4 = {0.f, 0.f, 0.f, 0.f};
  f32x4 acc[4][2];
#pragma unroll
  for (int m = 0; m < 4; ++m)
#pragma unroll
    for (int n = 0; n < 2; ++n) acc[m][n] = zero4;

  const int nk = K >> 5;
  lds_dma16(&As[0][w512],        a0);
  lds_dma16(&Bs[0][w512],        b0);
  lds_dma16(&Bs[0][2048 + w512], b1);
  __syncthreads();

  int cur = 0;
  for (int t = 0; t < nk; ++t) {
    if (t + 1 < nk) {
      const int kt = (t + 1) << 5;
      lds_dma16(&As[cur ^ 1][w512],        a0 + kt);
      lds_dma16(&Bs[cur ^ 1][w512],        b0 + kt);
      lds_dma16(&Bs[cur ^ 1][2048 + w512], b1 + kt);
    }
    s16x8 af[4], bfr[2];
#pragma unroll
    for (int m = 0; m < 4; ++m) {
      const int r = m * 16 + lo;
      af[m] = *(const s16x8*)&As[cur][r * 32 + ((hi ^ (r & 3))) * 8];
    }
#pragma unroll
    for (int n = 0; n < 2; ++n) {
      const int r = w * 32 + n * 16 + lo;
      bfr[n] = *(const s16x8*)&Bs[cur][r * 32 + ((hi ^ (r & 3))) * 8];
    }
#pragma unroll
    for (int m = 0; m < 4; ++m)
#pragma unroll
      for (int n = 0; n < 2; ++n)
        acc[m][n] = __builtin_amdgcn_mfma_f32_16x16x32_bf16(af[m], bfr[n], acc[m][n], 0, 0, 0);
    __syncthreads();
    cur ^= 1;
  }

#pragma unroll
  for (int m = 0; m < 4; ++m) {
#pragma unroll
    for (int n = 0; n < 2; ++n) {
      const long col = col0 + w * 32 + n * 16 + lo;
#pragma unroll
      for (int r = 0; r < 4; ++r) {
        const long row = row0 + m * 16 + hi * 4 + r;
        float v = acc[m][n][r];
        if constexpr (EPI == EPI_BF16) {
          Cb[row * N + col] = __float2bfloat16(v);
        } else if constexpr (EPI == EPI_GELU) {
          v += bias[col];
          v = 0.5f * v * (1.f + erff(v * 0.70710678118654752f));
          Cb[row * N + col] = __float2bfloat16(v);
        } else if constexpr (EPI == EPI_RES) {
          Cf[row * N + col] += v + bias[col];
        } else {
          if (col < Nreal) Cf[row * Nreal + col] = v + bias[col];
        }
      }
    }
  }
}

// ===========================================================================
// GEMM 256x128 (8 waves, dbuf, 48KB LDS, src-perm swizzle).
// r17: T4 counted-vmcnt pipeline — the old __syncthreads drained vmcnt(0),
// nullifying the dbuf prefetch (m97-ceiling mechanism). Now: raw s_barrier
// pair + s_waitcnt vmcnt(3) so the 3 prefetch loads stay in flight across
// the barrier. Race safety: barrier-1 after per-wave vmcnt(3) => all waves'
// DMA slices for buf[cur] retired before any ds_read; barrier-2 after MFMA
// => no STAGE overwrites a buffer still being read. sched_barrier(0) pins
// compiler motion (rule 18). Last iter waits vmcnt(0).
// ===========================================================================
template <int EPI>
__global__ __launch_bounds__(512)
void gemm_bt256(const bf16* __restrict__ A, const bf16* __restrict__ BT,
                const float* __restrict__ bias, float* Cf, bf16* Cb,
                int K, int N, int Nreal)
{
  __shared__ __align__(16) bf16 As[2][256 * 32];
  __shared__ __align__(16) bf16 Bs[2][128 * 32];
  const int tid = threadIdx.x;
  const int w = tid >> 6, l = tid & 63;
  const int lo = l & 15, hi = l >> 4;
  const int wm = (w & 3) * 64, wn = (w >> 2) * 64;   // 4x2 wave grid
  const long row0 = (long)blockIdx.y * 256;
  const long col0 = (long)blockIdx.x * 128;

  const int ss = ((tid & 3) ^ ((tid >> 2) & 3)) * 8;
  const bf16* a0 = A + (row0 + (tid >> 2)) * K + ss;
  const bf16* a1 = A + (row0 + 128 + (tid >> 2)) * K + ss;   // (row+128)&3 == row&3
  const bf16* b0 = BT + (col0 + (tid >> 2)) * K + ss;
  const int w512 = w * 512;

  const f32x4 zero4 = {0.f, 0.f, 0.f, 0.f};
  f32x4 acc[4][4];
#pragma unroll
  for (int m = 0; m < 4; ++m)
#pragma unroll
    for (int n = 0; n < 4; ++n) acc[m][n] = zero4;

  const int nk = K >> 5;
  lds_dma16(&As[0][w512],        a0);
  lds_dma16(&As[0][4096 + w512], a1);
  lds_dma16(&Bs[0][w512],        b0);
  // no drain here — loop's counted vmcnt handles buf0 readiness

  int cur = 0;
  for (int t = 0; t < nk; ++t) {
    if (t + 1 < nk) {
      const int kt = (t + 1) << 5;
      lds_dma16(&As[cur ^ 1][w512],        a0 + kt);
      lds_dma16(&As[cur ^ 1][4096 + w512], a1 + kt);
      lds_dma16(&Bs[cur ^ 1][w512],        b0 + kt);
      asm volatile("s_waitcnt vmcnt(3)" ::: "memory");   // buf[cur]'s 3 retired
    } else {
      asm volatile("s_waitcnt vmcnt(0)" ::: "memory");   // final tile: full drain
    }
    __builtin_amdgcn_sched_barrier(0);
    __builtin_amdgcn_s_barrier();        // all waves' buf[cur] slices written
    __builtin_amdgcn_sched_barrier(0);

    s16x8 af[4], bfr[4];
#pragma unroll
    for (int m = 0; m < 4; ++m) {
      const int r = wm + m * 16 + lo;
      af[m] = *(const s16x8*)&As[cur][r * 32 + ((hi ^ (r & 3))) * 8];
    }
#pragma unroll
    for (int n = 0; n < 4; ++n) {
      const int r = wn + n * 16 + lo;
      bfr[n] = *(const s16x8*)&Bs[cur][r * 32 + ((hi ^ (r & 3))) * 8];
    }
#pragma unroll
    for (int m = 0; m < 4; ++m)
#pragma unroll
      for (int n = 0; n < 4; ++n)
        acc[m][n] = __builtin_amdgcn_mfma_f32_16x16x32_bf16(af[m], bfr[n], acc[m][n], 0, 0, 0);

    __builtin_amdgcn_sched_barrier(0);
    __builtin_amdgcn_s_barrier();        // all reads of buf[cur] done
    __builtin_amdgcn_sched_barrier(0);
    cur ^= 1;
  }

#pragma unroll
  for (int m = 0; m < 4; ++m) {
#pragma unroll
    for (int n = 0; n < 4; ++n) {
      const long col = col0 + wn + n * 16 + lo;
#pragma unroll
      for (int r = 0; r < 4; ++r) {
        const long row = row0 + wm + m * 16 + hi * 4 + r;
        float v = acc[m][n][r];
        if constexpr (EPI == EPI_BF16) {
          Cb[row * N + col] = __float2bfloat16(v);
        } else if constexpr (EPI == EPI_GELU) {
          v += bias[col];
          v = 0.5f * v * (1.f + erff(v * 0.70710678118654752f));
          Cb[row * N + col] = __float2bfloat16(v);
        } else {  // EPI_HEAD
          if (col < Nreal) Cf[row * Nreal + col] = v + bias[col];
        }
      }
    }
  }
}

// ===========================================================================
// Flash attention, causal — verified r14 (XOR bank-swizzle Kl/Vl/Pl +
// heavy-first dispatch).
// ===========================================================================
__global__ __launch_bounds__(256)
void attn_kernel(const bf16* __restrict__ qkv, bf16* __restrict__ o)
{
  __shared__ __align__(16) bf16 Kl[64 * 64];
  __shared__ __align__(16) bf16 Vl[64 * 64];
  __shared__ __align__(16) bf16 Pl[4][32 * 64];
  const int tid = threadIdx.x;
  const int w = tid >> 6, l = tid & 63;
  const int lo = l & 15, hi = l >> 4;
  const int q0 = (7 - blockIdx.x) * 128;     // heavy-first
  const int b = blockIdx.y / 12, h = blockIdx.y % 12;
  const int wq0 = q0 + w * 32;
  const bf16* base = qkv + (long)b * 1024 * 2304;

  s16x8 qf[2][2];
#pragma unroll
  for (int m = 0; m < 2; ++m)
#pragma unroll
    for (int ks = 0; ks < 2; ++ks)
      qf[m][ks] = *(const s16x8*)(base + (long)(wq0 + m * 16 + lo) * 2304 + h * 64 + ks * 32 + hi * 8);

  const f32x4 zero4 = {0.f, 0.f, 0.f, 0.f};
  f32x4 oacc[2][4];
  float mst[2][4], lst[2][4];
#pragma unroll
  for (int m = 0; m < 2; ++m) {
#pragma unroll
    for (int n = 0; n < 4; ++n) oacc[m][n] = zero4;
#pragma unroll
    for (int r = 0; r < 4; ++r) { mst[m][r] = -3.0e38f; lst[m][r] = 0.f; }
  }

  const int cB = tid + 256;
  const int r0c = tid >> 3, sl0 = (tid & 7) ^ (r0c & 7);
  const int r1c = cB >> 3,  sl1 = (cB & 7) ^ (r1c & 7);

  const int nt = (q0 + 128) / 64;
  for (int t = 0; t < nt; ++t) {
    const int j0 = t * 64;
    const s16x8 rk0 = *(const s16x8*)(base + (long)(j0 + r0c) * 2304 +  768 + h * 64 + (tid & 7) * 8);
    const s16x8 rk1 = *(const s16x8*)(base + (long)(j0 + r1c) * 2304 +  768 + h * 64 + (cB  & 7) * 8);
    const s16x8 rv0 = *(const s16x8*)(base + (long)(j0 + r0c) * 2304 + 1536 + h * 64 + (tid & 7) * 8);
    const s16x8 rv1 = *(const s16x8*)(base + (long)(j0 + r1c) * 2304 + 1536 + h * 64 + (cB  & 7) * 8);
    __syncthreads();
    *(s16x8*)&Kl[r0c * 64 + sl0 * 8] = rk0;
    *(s16x8*)&Kl[r1c * 64 + sl1 * 8] = rk1;
    *(s16x8*)&Vl[r0c * 64 + sl0 * 8] = rv0;
    *(s16x8*)&Vl[r1c * 64 + sl1 * 8] = rv1;
    __syncthreads();

    if (j0 <= wq0 + 31) {
      f32x4 s[2][4];
#pragma unroll
      for (int m = 0; m < 2; ++m)
#pragma unroll
        for (int n = 0; n < 4; ++n) s[m][n] = zero4;
#pragma unroll
      for (int ks = 0; ks < 2; ++ks) {
        s16x8 kf[4];
#pragma unroll
        for (int n = 0; n < 4; ++n) {
          const int r = n * 16 + lo;
          kf[n] = *(const s16x8*)&Kl[r * 64 + ((ks * 4 + hi) ^ (r & 7)) * 8];
        }
#pragma unroll
        for (int m = 0; m < 2; ++m)
#pragma unroll
          for (int n = 0; n < 4; ++n)
            s[m][n] = __builtin_amdgcn_mfma_f32_16x16x32_bf16(qf[m][ks], kf[n], s[m][n], 0, 0, 0);
      }
      const bool edge = (j0 + 63 > wq0);
#pragma unroll
      for (int m = 0; m < 2; ++m)
#pragma unroll
        for (int n = 0; n < 4; ++n) {
          const int j = j0 + n * 16 + lo;
#pragma unroll
          for (int r = 0; r < 4; ++r) {
            float v = s[m][n][r] * SCALE_QK;
            if (edge && j > wq0 + m * 16 + hi * 4 + r) v = NEG_BIG;
            s[m][n][r] = v;
          }
        }
#pragma unroll
      for (int m = 0; m < 2; ++m)
#pragma unroll
        for (int r = 0; r < 4; ++r) {
          float x = fmaxf(fmaxf(s[m][0][r], s[m][1][r]), fmaxf(s[m][2][r], s[m][3][r]));
          x = fmaxf(x, __shfl_xor(x, 1));
          x = fmaxf(x, __shfl_xor(x, 2));
          x = fmaxf(x, __shfl_xor(x, 4));
          x = fmaxf(x, __shfl_xor(x, 8));
          const float mn = fmaxf(mst[m][r], x);
          const float corr = __expf(mst[m][r] - mn);
          mst[m][r] = mn;
          float rs = 0.f;
#pragma unroll
          for (int n = 0; n < 4; ++n) {
            float p = __expf(s[m][n][r] - mn);
            s[m][n][r] = p;
            rs += p;
          }
          rs += __shfl_xor(rs, 1);
          rs += __shfl_xor(rs, 2);
          rs += __shfl_xor(rs, 4);
          rs += __shfl_xor(rs, 8);
          lst[m][r] = lst[m][r] * corr + rs;
#pragma unroll
          for (int n = 0; n < 4; ++n) oacc[m][n][r] *= corr;
        }
#pragma unroll
      for (int m = 0; m < 2; ++m)
#pragma unroll
        for (int n = 0; n < 4; ++n)
#pragma unroll
          for (int r = 0; r < 4; ++r) {
            const int pr = m * 16 + hi * 4 + r;
            const int pc = n * 16 + lo;
            Pl[w][pr * 64 + ((pc >> 3) ^ (pr & 7)) * 8 + (pc & 7)] =
                __float2bfloat16(s[m][n][r]);
          }
      s16x8 pa[2][2];
#pragma unroll
      for (int m = 0; m < 2; ++m)
#pragma unroll
        for (int ks = 0; ks < 2; ++ks) {
          const int r = m * 16 + lo;
          pa[m][ks] = *(const s16x8*)&Pl[w][r * 64 + ((ks * 4 + hi) ^ (r & 7)) * 8];
        }
#pragma unroll
      for (int ks = 0; ks < 2; ++ks)
#pragma unroll
        for (int n = 0; n < 4; ++n) {
          s16x8 vf;
#pragma unroll
          for (int j = 0; j < 8; ++j) {
            const int vr = ks * 32 + hi * 8 + j;
            const int vd = n * 16 + lo;
            vf[j] = *(const short*)&Vl[vr * 64 + ((vd >> 3) ^ (vr & 7)) * 8 + (vd & 7)];
          }
#pragma unroll
          for (int m = 0; m < 2; ++m)
            oacc[m][n] = __builtin_amdgcn_mfma_f32_16x16x32_bf16(pa[m][ks], vf, oacc[m][n], 0, 0, 0);
        }
    }
  }
#pragma unroll
  for (int m = 0; m < 2; ++m)
#pragma unroll
    for (int n = 0; n < 4; ++n)
#pragma unroll
      for (int r = 0; r < 4; ++r) {
        const int q = wq0 + m * 16 + hi * 4 + r;
        o[(long)(b * 1024 + q) * 768 + h * 64 + n * 16 + lo] =
            __float2bfloat16(oacc[m][n][r] / lst[m][r]);
      }
}

// ===========================================================================
// helpers
// ===========================================================================
__global__ void detect_idx(const int* __restrict__ idx, int* __restrict__ flag)
{
  const int t = threadIdx.x;
  const int v = idx[2 * t + 1];
  const unsigned long long nz = __ballot(v != 0);
  if (t == 0) flag[0] = (nz == 0ull) ? 1 : 0;
}

__global__ __launch_bounds__(192)
void embed_kernel(const int* __restrict__ idx, const float* __restrict__ tok,
                  const float* __restrict__ pos, float* __restrict__ x,
                  const int* __restrict__ flag)
{
  const int row = blockIdx.x;
  const int t = row & 1023;
  const int id = flag[0] ? idx[2 * row] : idx[row];
  const int e = threadIdx.x * 4;
  const float4 a = *(const float4*)&tok[(long)id * 768 + e];
  const float4 p = *(const float4*)&pos[(long)t * 768 + e];
  float4 r; r.x = a.x + p.x; r.y = a.y + p.y; r.z = a.z + p.z; r.w = a.w + p.w;
  *(float4*)&x[(long)row * 768 + e] = r;
}

// wave-per-row LN body (4 rows per 256-thread block slice)
__device__ __forceinline__ void ln_rows(const float* __restrict__ x,
                                        const float* __restrict__ g,
                                        const float* __restrict__ bt,
                                        bf16* __restrict__ out,
                                        int row4, int tid)
{
  const int lane = tid & 63;
  const int row = row4 * 4 + (tid >> 6);
  const float* xr = x + (long)row * 768;
  f32x4 v[3];
  float s = 0.f, q = 0.f;
#pragma unroll
  for (int p = 0; p < 3; ++p) {
    v[p] = *(const f32x4*)&xr[lane * 4 + p * 256];
#pragma unroll
    for (int j = 0; j < 4; ++j) { s += v[p][j]; q += v[p][j] * v[p][j]; }
  }
#pragma unroll
  for (int o = 32; o > 0; o >>= 1) { s += __shfl_xor(s, o); q += __shfl_xor(q, o); }
  const float mu = s * (1.f / 768.f);
  const float var = q * (1.f / 768.f) - mu * mu;
  const float rs = rsqrtf(var + 1e-8f);
  bf16* orow = out + (long)row * 768;
#pragma unroll
  for (int p = 0; p < 3; ++p) {
    const int e = lane * 4 + p * 256;
    s16x4 pk;
#pragma unroll
    for (int j = 0; j < 4; ++j) {
      bf16 t = __float2bfloat16((v[p][j] - mu) * rs * g[e + j] + bt[e + j]);
      pk[j] = *(const short*)&t;
    }
    *(s16x4*)&orow[e] = pk;
  }
}

__global__ __launch_bounds__(256)
void ln_kernel(const float* __restrict__ x, const float* __restrict__ g,
               const float* __restrict__ bt, bf16* __restrict__ out)
{
  ln_rows(x, g, bt, out, blockIdx.x, threadIdx.x);
}

// 64x64 fp32->bf16 transpose tile
__device__ __forceinline__ void tile_tr64(const float* __restrict__ ip,
                                          bf16* __restrict__ op,
                                          int R, int Creal, int r0, int c0,
                                          int tid, float (*tile)[65])
{
  const int tx = tid & 63, ty = tid >> 6;
#pragma unroll
  for (int p = 0; p < 16; ++p) {
    const int r = p * 4 + ty;
    const int c = c0 + tx;
    tile[r][tx] = (c < Creal) ? ip[(long)(r0 + r) * Creal + c] : 0.f;
  }
  __syncthreads();
#pragma unroll
  for (int p = 0; p < 16; ++p) {
    const int cc = p * 4 + ty;
    op[(long)(c0 + cc) * R + r0 + tx] = __float2bfloat16(tile[tx][cc]);
  }
}

__global__ __launch_bounds__(256)
void transpose_conv(const float* __restrict__ in, bf16* __restrict__ out,
                    int R, int Creal)
{
  __shared__ float tile[64][65];
  tile_tr64(in, out, R, Creal, blockIdx.y * 64, blockIdx.x * 64, threadIdx.x, tile);
}

// per-layer weight repacks + FUSED LN1 (verified r16): blocks 0..1727 repack
// (qkv 432 | proj 144 | w1 576 | w2 576); 1728..2751 LN1.
__global__ __launch_bounds__(256)
void repack_layer(const float* __restrict__ wq, const float* __restrict__ wk,
                  const float* __restrict__ wv, const float* __restrict__ projw,
                  const float* __restrict__ w1, const float* __restrict__ w2,
                  const float* __restrict__ x, const float* __restrict__ ln1g,
                  const float* __restrict__ ln1b,
                  bf16* __restrict__ WqkvT, bf16* __restrict__ WprojT,
                  bf16* __restrict__ W1T, bf16* __restrict__ W2T,
                  bf16* __restrict__ xn)
{
  __shared__ float tile[64][65];
  const int tid = threadIdx.x;
  const int t = blockIdx.x;
  if (t < 432) {
    const int op_i = t / 144, r = t % 144;
    const int h = r / 12, ry = r % 12;
    const float* ip = (op_i == 0 ? wq : op_i == 1 ? wk : wv) + h * 49152;
    bf16* op = WqkvT + (long)op_i * 768 * 768 + (long)h * 64 * 768;
    tile_tr64(ip, op, 768, 64, ry * 64, 0, tid, tile);
  } else if (t < 576) {
    const int t2 = t - 432;
    const int r0 = (t2 / 12) * 64, c0 = (t2 % 12) * 64;
#pragma unroll
    for (int p = 0; p < 4; ++p) {
      const int row = r0 + p * 16 + (tid >> 4);
      const int col = c0 + (tid & 15) * 4;
      const float4 v = *(const float4*)&projw[(long)row * 768 + col];
      bf16 t0 = __float2bfloat16(v.x), t1 = __float2bfloat16(v.y);
      bf16 t2b = __float2bfloat16(v.z), t3 = __float2bfloat16(v.w);
      s16x4 pk;
      pk[0] = *(const short*)&t0; pk[1] = *(const short*)&t1;
      pk[2] = *(const short*)&t2b; pk[3] = *(const short*)&t3;
      *(s16x4*)&WprojT[(long)row * 768 + col] = pk;
    }
  } else if (t < 1152) {
    const int t3 = t - 576;
    tile_tr64(w1, W1T, 768, 3072, (t3 / 48) * 64, (t3 % 48) * 64, tid, tile);
  } else if (t < 1728) {
    const int t4 = t - 1152;
    tile_tr64(w2, W2T, 3072, 768, (t4 / 12) * 64, (t4 % 12) * 64, tid, tile);
  } else {
    ln_rows(x, ln1g, ln1b, xn, t - 1728, tid);   // fused LN1
  }
}

// ===========================================================================
extern "C" void kernel_launch(void* const* d_in, const int* in_sizes, int n_in,
                              void* d_out, int out_size, void* d_ws, size_t ws_size,
                              hipStream_t stream)
{
  (void)in_sizes; (void)n_in; (void)out_size; (void)ws_size;
  const int*   idx   = (const int*)d_in[0];
  const float* tok   = (const float*)d_in[1];
  const float* pos   = (const float*)d_in[2];
  const float* wq    = (const float*)d_in[3];
  const float* wk    = (const float*)d_in[4];
  const float* wv    = (const float*)d_in[5];
  const float* projw = (const float*)d_in[6];
  const float* projb = (const float*)d_in[7];
  const float* ln1g  = (const float*)d_in[8];
  const float* ln1b  = (const float*)d_in[9];
  const float* ln2g  = (const float*)d_in[10];
  const float* ln2b  = (const float*)d_in[11];
  const float* w1    = (const float*)d_in[12];
  const float* b1    = (const float*)d_in[13];
  const float* w2    = (const float*)d_in[14];
  const float* b2    = (const float*)d_in[15];
  const float* lnfg  = (const float*)d_in[16];
  const float* lnfb  = (const float*)d_in[17];
  const float* headw = (const float*)d_in[18];
  const float* headb = (const float*)d_in[19];
  float* out = (float*)d_out;

  char* ws = (char*)d_ws;
  size_t off = 0;
  auto alloc = [&](size_t bytes) -> void* {
    void* p = ws + off; off += (bytes + 255) & ~(size_t)255; return p;
  };
  int*   iflag  = (int*)  alloc(256);
  float* x      = (float*)alloc(4096ull * 768 * 4);
  bf16*  xn     = (bf16*) alloc(4096ull * 768 * 2);
  bf16*  qkvb   = (bf16*) alloc(4096ull * 2304 * 2);
  bf16*  ob     = (bf16*) alloc(4096ull * 768 * 2);
  bf16*  hb     = (bf16*) alloc(4096ull * 3072 * 2);
  bf16*  WqkvT  = (bf16*) alloc(2304ull * 768 * 2);
  bf16*  WprojT = (bf16*) alloc(768ull * 768 * 2);
  bf16*  W1T    = (bf16*) alloc(3072ull * 768 * 2);
  bf16*  W2T    = (bf16*) alloc(768ull * 3072 * 2);
  bf16*  headT  = (bf16*) alloc(50304ull * 768 * 2);

  detect_idx<<<1, 64, 0, stream>>>(idx, iflag);
  transpose_conv<<<dim3(786, 12), 256, 0, stream>>>(headw, headT, 768, 50257);
  embed_kernel<<<4096, 192, 0, stream>>>(idx, tok, pos, x, iflag);

  for (int l = 0; l < 12; ++l) {
    const size_t hOff = (size_t)l * 12 * 768 * 64;
    repack_layer<<<2752, 256, 0, stream>>>(wq + hOff, wk + hOff, wv + hOff,
                                           projw + (size_t)l * 768 * 768,
                                           w1 + (size_t)l * 768 * 3072,
                                           w2 + (size_t)l * 3072 * 768,
                                           x, ln1g + l * 768, ln1b + l * 768,
                                           WqkvT, WprojT, W1T, W2T, xn);

    gemm_bt256<EPI_BF16><<<dim3(18, 16), 512, 0, stream>>>(xn, WqkvT, nullptr, nullptr, qkvb, 768, 2304, 2304);
    attn_kernel<<<dim3(8, 48), 256, 0, stream>>>(qkvb, ob);
    gemm_bt64<EPI_RES><<<dim3(6, 64), 256, 0, stream>>>(ob, WprojT, projb + l * 768, x, nullptr, 4096, 768, 768, 768);
    ln_kernel<<<1024, 256, 0, stream>>>(x, ln2g + l * 768, ln2b + l * 768, xn);
    gemm_bt256<EPI_GELU><<<dim3(24, 16), 512, 0, stream>>>(xn, W1T, b1 + (size_t)l * 3072, nullptr, hb, 768, 3072, 3072);
    gemm_bt64<EPI_RES><<<dim3(6, 64), 256, 0, stream>>>(hb, W2T, b2 + l * 768, x, nullptr, 4096, 768, 3072, 768);
  }

  ln_kernel<<<1024, 256, 0, stream>>>(x, lnfg, lnfb, xn);
  gemm_bt256<EPI_HEAD><<<dim3(393, 16), 512, 0, stream>>>(xn, headT, headb, out, nullptr, 768, 50304, 50257);
}

// Round 18
// 3218.595 us; speedup vs baseline: 1.0268x; 1.0268x over previous
//
#include <hip/hip_runtime.h>
#include <hip/hip_bf16.h>
#include <stdint.h>
#include <math.h>

typedef __hip_bfloat16 bf16;
typedef short s16x8 __attribute__((ext_vector_type(8)));
typedef short s16x4 __attribute__((ext_vector_type(4)));
typedef float f32x4 __attribute__((ext_vector_type(4)));

#define SCALE_QK 0.03608439182435161f   /* 768^-0.5 (ref scales by n_embd^-0.5) */
#define NEG_BIG  -1.0e30f

// ---------------------------------------------------------------------------
// async global->LDS, 16B per lane (verified r4/r5/r7).
// ---------------------------------------------------------------------------
__device__ __forceinline__ void lds_dma16(void* lds_uniform, const void* gsrc) {
  __builtin_amdgcn_global_load_lds(
      (const __attribute__((address_space(1))) unsigned int*)(uintptr_t)gsrc,
      (__attribute__((address_space(3))) unsigned int*)(unsigned int)(uintptr_t)lds_uniform,
      16, 0, 0);
}

enum { EPI_BF16 = 0, EPI_GELU = 1, EPI_RES = 2, EPI_HEAD = 3 };

// ===========================================================================
// GEMM 64x128 (4 waves, dbuf, src-perm swizzle) — verified r13/r14/r16.
// proj/mlp2 (N=768). (r15 lesson: split-K atomics regressed — reverted.)
// ===========================================================================
template <int EPI>
__global__ __launch_bounds__(256)
void gemm_bt64(const bf16* __restrict__ A, const bf16* __restrict__ BT,
               const float* __restrict__ bias, float* Cf, bf16* Cb,
               int M, int N, int K, int Nreal)
{
  __shared__ __align__(16) bf16 As[2][64 * 32];
  __shared__ __align__(16) bf16 Bs[2][128 * 32];
  const int tid = threadIdx.x;
  const int w = tid >> 6, l = tid & 63;
  const int lo = l & 15, hi = l >> 4;
  const long row0 = (long)blockIdx.y * 64;
  const long col0 = (long)blockIdx.x * 128;

  const int c0 = w * 64 + l, c1 = c0 + 256;
  const int s0 = ((c0 & 3) ^ ((c0 >> 2) & 3)) * 8;
  const int s1 = ((c1 & 3) ^ ((c1 >> 2) & 3)) * 8;
  const bf16* a0 = A + (row0 + (c0 >> 2)) * K + s0;
  const bf16* b0 = BT + (col0 + (c0 >> 2)) * K + s0;
  const bf16* b1 = BT + (col0 + (c1 >> 2)) * K + s1;
  const int w512 = w * 512;

  const f32x4 zero4 = {0.f, 0.f, 0.f, 0.f};
  f32x4 acc[4][2];
#pragma unroll
  for (int m = 0; m < 4; ++m)
#pragma unroll
    for (int n = 0; n < 2; ++n) acc[m][n] = zero4;

  const int nk = K >> 5;
  lds_dma16(&As[0][w512],        a0);
  lds_dma16(&Bs[0][w512],        b0);
  lds_dma16(&Bs[0][2048 + w512], b1);
  __syncthreads();

  int cur = 0;
  for (int t = 0; t < nk; ++t) {
    if (t + 1 < nk) {
      const int kt = (t + 1) << 5;
      lds_dma16(&As[cur ^ 1][w512],        a0 + kt);
      lds_dma16(&Bs[cur ^ 1][w512],        b0 + kt);
      lds_dma16(&Bs[cur ^ 1][2048 + w512], b1 + kt);
    }
    s16x8 af[4], bfr[2];
#pragma unroll
    for (int m = 0; m < 4; ++m) {
      const int r = m * 16 + lo;
      af[m] = *(const s16x8*)&As[cur][r * 32 + ((hi ^ (r & 3))) * 8];
    }
#pragma unroll
    for (int n = 0; n < 2; ++n) {
      const int r = w * 32 + n * 16 + lo;
      bfr[n] = *(const s16x8*)&Bs[cur][r * 32 + ((hi ^ (r & 3))) * 8];
    }
#pragma unroll
    for (int m = 0; m < 4; ++m)
#pragma unroll
      for (int n = 0; n < 2; ++n)
        acc[m][n] = __builtin_amdgcn_mfma_f32_16x16x32_bf16(af[m], bfr[n], acc[m][n], 0, 0, 0);
    __syncthreads();
    cur ^= 1;
  }

#pragma unroll
  for (int m = 0; m < 4; ++m) {
#pragma unroll
    for (int n = 0; n < 2; ++n) {
      const long col = col0 + w * 32 + n * 16 + lo;
#pragma unroll
      for (int r = 0; r < 4; ++r) {
        const long row = row0 + m * 16 + hi * 4 + r;
        float v = acc[m][n][r];
        if constexpr (EPI == EPI_BF16) {
          Cb[row * N + col] = __float2bfloat16(v);
        } else if constexpr (EPI == EPI_GELU) {
          v += bias[col];
          v = 0.5f * v * (1.f + erff(v * 0.70710678118654752f));
          Cb[row * N + col] = __float2bfloat16(v);
        } else if constexpr (EPI == EPI_RES) {
          Cf[row * N + col] += v + bias[col];
        } else {
          if (col < Nreal) Cf[row * Nreal + col] = v + bias[col];
        }
      }
    }
  }
}

// ===========================================================================
// GEMM 256x128 (8 waves, dbuf, 48KB LDS, src-perm swizzle) + r17 counted
// vmcnt (neutral-to-mildly-positive on head; kept).
// ===========================================================================
template <int EPI>
__global__ __launch_bounds__(512)
void gemm_bt256(const bf16* __restrict__ A, const bf16* __restrict__ BT,
                const float* __restrict__ bias, float* Cf, bf16* Cb,
                int K, int N, int Nreal)
{
  __shared__ __align__(16) bf16 As[2][256 * 32];
  __shared__ __align__(16) bf16 Bs[2][128 * 32];
  const int tid = threadIdx.x;
  const int w = tid >> 6, l = tid & 63;
  const int lo = l & 15, hi = l >> 4;
  const int wm = (w & 3) * 64, wn = (w >> 2) * 64;   // 4x2 wave grid
  const long row0 = (long)blockIdx.y * 256;
  const long col0 = (long)blockIdx.x * 128;

  const int ss = ((tid & 3) ^ ((tid >> 2) & 3)) * 8;
  const bf16* a0 = A + (row0 + (tid >> 2)) * K + ss;
  const bf16* a1 = A + (row0 + 128 + (tid >> 2)) * K + ss;   // (row+128)&3 == row&3
  const bf16* b0 = BT + (col0 + (tid >> 2)) * K + ss;
  const int w512 = w * 512;

  const f32x4 zero4 = {0.f, 0.f, 0.f, 0.f};
  f32x4 acc[4][4];
#pragma unroll
  for (int m = 0; m < 4; ++m)
#pragma unroll
    for (int n = 0; n < 4; ++n) acc[m][n] = zero4;

  const int nk = K >> 5;
  lds_dma16(&As[0][w512],        a0);
  lds_dma16(&As[0][4096 + w512], a1);
  lds_dma16(&Bs[0][w512],        b0);

  int cur = 0;
  for (int t = 0; t < nk; ++t) {
    if (t + 1 < nk) {
      const int kt = (t + 1) << 5;
      lds_dma16(&As[cur ^ 1][w512],        a0 + kt);
      lds_dma16(&As[cur ^ 1][4096 + w512], a1 + kt);
      lds_dma16(&Bs[cur ^ 1][w512],        b0 + kt);
      asm volatile("s_waitcnt vmcnt(3)" ::: "memory");   // buf[cur]'s 3 retired
    } else {
      asm volatile("s_waitcnt vmcnt(0)" ::: "memory");   // final tile: full drain
    }
    __builtin_amdgcn_sched_barrier(0);
    __builtin_amdgcn_s_barrier();        // all waves' buf[cur] slices written
    __builtin_amdgcn_sched_barrier(0);

    s16x8 af[4], bfr[4];
#pragma unroll
    for (int m = 0; m < 4; ++m) {
      const int r = wm + m * 16 + lo;
      af[m] = *(const s16x8*)&As[cur][r * 32 + ((hi ^ (r & 3))) * 8];
    }
#pragma unroll
    for (int n = 0; n < 4; ++n) {
      const int r = wn + n * 16 + lo;
      bfr[n] = *(const s16x8*)&Bs[cur][r * 32 + ((hi ^ (r & 3))) * 8];
    }
#pragma unroll
    for (int m = 0; m < 4; ++m)
#pragma unroll
      for (int n = 0; n < 4; ++n)
        acc[m][n] = __builtin_amdgcn_mfma_f32_16x16x32_bf16(af[m], bfr[n], acc[m][n], 0, 0, 0);

    __builtin_amdgcn_sched_barrier(0);
    __builtin_amdgcn_s_barrier();        // all reads of buf[cur] done
    __builtin_amdgcn_sched_barrier(0);
    cur ^= 1;
  }

#pragma unroll
  for (int m = 0; m < 4; ++m) {
#pragma unroll
    for (int n = 0; n < 4; ++n) {
      const long col = col0 + wn + n * 16 + lo;
#pragma unroll
      for (int r = 0; r < 4; ++r) {
        const long row = row0 + wm + m * 16 + hi * 4 + r;
        float v = acc[m][n][r];
        if constexpr (EPI == EPI_BF16) {
          Cb[row * N + col] = __float2bfloat16(v);
        } else if constexpr (EPI == EPI_GELU) {
          v += bias[col];
          v = 0.5f * v * (1.f + erff(v * 0.70710678118654752f));
          Cb[row * N + col] = __float2bfloat16(v);
        } else {  // EPI_HEAD
          if (col < Nreal) Cf[row * Nreal + col] = v + bias[col];
        }
      }
    }
  }
}

// ===========================================================================
// Flash attention, causal. r18: V stored TRANSPOSED in LDS (Vt[d][j]) so
// each PV B-fragment is ONE ds_read_b128 instead of 8 scalar ds_read_u16
// (was 64 scalar reads/thread/tile ≈ 4.6x the MFMA cost). Slot map
// slot(d,j) = ((j>>3) ^ (d&7) ^ ((d>>3)&7)) & 7 gives conflict-free scalar
// writes (each write instr covers all 64 elem-offsets once => 2 lanes/bank)
// and spread b128 reads. Logical vf element order identical to r14-verified.
// K tile + P tile keep the r14 row-swizzle. Heavy-first dispatch retained.
// ===========================================================================
__global__ __launch_bounds__(256)
void attn_kernel(const bf16* __restrict__ qkv, bf16* __restrict__ o)
{
  __shared__ __align__(16) bf16 Kl[64 * 64];
  __shared__ __align__(16) bf16 Vl[64 * 64];   // transposed: rows d, cols j
  __shared__ __align__(16) bf16 Pl[4][32 * 64];
  const int tid = threadIdx.x;
  const int w = tid >> 6, l = tid & 63;
  const int lo = l & 15, hi = l >> 4;
  const int q0 = (7 - blockIdx.x) * 128;     // heavy-first
  const int b = blockIdx.y / 12, h = blockIdx.y % 12;
  const int wq0 = q0 + w * 32;
  const bf16* base = qkv + (long)b * 1024 * 2304;
  short* Vls = (short*)Vl;

  s16x8 qf[2][2];
#pragma unroll
  for (int m = 0; m < 2; ++m)
#pragma unroll
    for (int ks = 0; ks < 2; ++ks)
      qf[m][ks] = *(const s16x8*)(base + (long)(wq0 + m * 16 + lo) * 2304 + h * 64 + ks * 32 + hi * 8);

  const f32x4 zero4 = {0.f, 0.f, 0.f, 0.f};
  f32x4 oacc[2][4];
  float mst[2][4], lst[2][4];
#pragma unroll
  for (int m = 0; m < 2; ++m) {
#pragma unroll
    for (int n = 0; n < 4; ++n) oacc[m][n] = zero4;
#pragma unroll
    for (int r = 0; r < 4; ++r) { mst[m][r] = -3.0e38f; lst[m][r] = 0.f; }
  }

  const int cB = tid + 256;
  const int r0c = tid >> 3, sl0 = (tid & 7) ^ (r0c & 7);
  const int r1c = cB >> 3,  sl1 = (cB & 7) ^ (r1c & 7);
  const int tk = tid & 7;                    // == cB & 7; V col-chunk d/8

  const int nt = (q0 + 128) / 64;
  for (int t = 0; t < nt; ++t) {
    const int j0 = t * 64;
    const s16x8 rk0 = *(const s16x8*)(base + (long)(j0 + r0c) * 2304 +  768 + h * 64 + (tid & 7) * 8);
    const s16x8 rk1 = *(const s16x8*)(base + (long)(j0 + r1c) * 2304 +  768 + h * 64 + (cB  & 7) * 8);
    const s16x8 rv0 = *(const s16x8*)(base + (long)(j0 + r0c) * 2304 + 1536 + h * 64 + (tid & 7) * 8);
    const s16x8 rv1 = *(const s16x8*)(base + (long)(j0 + r1c) * 2304 + 1536 + h * 64 + (cB  & 7) * 8);
    __syncthreads();
    *(s16x8*)&Kl[r0c * 64 + sl0 * 8] = rk0;
    *(s16x8*)&Kl[r1c * 64 + sl1 * 8] = rk1;
    // V transposed store: rv holds V[j=r?c][d=tk*8 .. +7] -> Vt[d][j]
#pragma unroll
    for (int e = 0; e < 8; ++e) {
      Vls[(tk * 8 + e) * 64 + (((r0c >> 3) ^ e ^ tk) & 7) * 8 + (r0c & 7)] = rv0[e];
      Vls[(tk * 8 + e) * 64 + (((r1c >> 3) ^ e ^ tk) & 7) * 8 + (r1c & 7)] = rv1[e];
    }
    __syncthreads();

    if (j0 <= wq0 + 31) {
      f32x4 s[2][4];
#pragma unroll
      for (int m = 0; m < 2; ++m)
#pragma unroll
        for (int n = 0; n < 4; ++n) s[m][n] = zero4;
#pragma unroll
      for (int ks = 0; ks < 2; ++ks) {
        s16x8 kf[4];
#pragma unroll
        for (int n = 0; n < 4; ++n) {
          const int r = n * 16 + lo;
          kf[n] = *(const s16x8*)&Kl[r * 64 + ((ks * 4 + hi) ^ (r & 7)) * 8];
        }
#pragma unroll
        for (int m = 0; m < 2; ++m)
#pragma unroll
          for (int n = 0; n < 4; ++n)
            s[m][n] = __builtin_amdgcn_mfma_f32_16x16x32_bf16(qf[m][ks], kf[n], s[m][n], 0, 0, 0);
      }
      const bool edge = (j0 + 63 > wq0);
#pragma unroll
      for (int m = 0; m < 2; ++m)
#pragma unroll
        for (int n = 0; n < 4; ++n) {
          const int j = j0 + n * 16 + lo;
#pragma unroll
          for (int r = 0; r < 4; ++r) {
            float v = s[m][n][r] * SCALE_QK;
            if (edge && j > wq0 + m * 16 + hi * 4 + r) v = NEG_BIG;
            s[m][n][r] = v;
          }
        }
#pragma unroll
      for (int m = 0; m < 2; ++m)
#pragma unroll
        for (int r = 0; r < 4; ++r) {
          float x = fmaxf(fmaxf(s[m][0][r], s[m][1][r]), fmaxf(s[m][2][r], s[m][3][r]));
          x = fmaxf(x, __shfl_xor(x, 1));
          x = fmaxf(x, __shfl_xor(x, 2));
          x = fmaxf(x, __shfl_xor(x, 4));
          x = fmaxf(x, __shfl_xor(x, 8));
          const float mn = fmaxf(mst[m][r], x);
          const float corr = __expf(mst[m][r] - mn);
          mst[m][r] = mn;
          float rs = 0.f;
#pragma unroll
          for (int n = 0; n < 4; ++n) {
            float p = __expf(s[m][n][r] - mn);
            s[m][n][r] = p;
            rs += p;
          }
          rs += __shfl_xor(rs, 1);
          rs += __shfl_xor(rs, 2);
          rs += __shfl_xor(rs, 4);
          rs += __shfl_xor(rs, 8);
          lst[m][r] = lst[m][r] * corr + rs;
#pragma unroll
          for (int n = 0; n < 4; ++n) oacc[m][n][r] *= corr;
        }
#pragma unroll
      for (int m = 0; m < 2; ++m)
#pragma unroll
        for (int n = 0; n < 4; ++n)
#pragma unroll
          for (int r = 0; r < 4; ++r) {
            const int pr = m * 16 + hi * 4 + r;
            const int pc = n * 16 + lo;
            Pl[w][pr * 64 + ((pc >> 3) ^ (pr & 7)) * 8 + (pc & 7)] =
                __float2bfloat16(s[m][n][r]);
          }
      s16x8 pa[2][2];
#pragma unroll
      for (int m = 0; m < 2; ++m)
#pragma unroll
        for (int ks = 0; ks < 2; ++ks) {
          const int r = m * 16 + lo;
          pa[m][ks] = *(const s16x8*)&Pl[w][r * 64 + ((ks * 4 + hi) ^ (r & 7)) * 8];
        }
#pragma unroll
      for (int ks = 0; ks < 2; ++ks)
#pragma unroll
        for (int n = 0; n < 4; ++n) {
          const int d = n * 16 + lo;
          const int slot = ((ks * 4 + hi) ^ (d & 7) ^ ((d >> 3) & 7)) & 7;
          const s16x8 vf = *(const s16x8*)&Vl[d * 64 + slot * 8];
#pragma unroll
          for (int m = 0; m < 2; ++m)
            oacc[m][n] = __builtin_amdgcn_mfma_f32_16x16x32_bf16(pa[m][ks], vf, oacc[m][n], 0, 0, 0);
        }
    }
  }
#pragma unroll
  for (int m = 0; m < 2; ++m)
#pragma unroll
    for (int n = 0; n < 4; ++n)
#pragma unroll
      for (int r = 0; r < 4; ++r) {
        const int q = wq0 + m * 16 + hi * 4 + r;
        o[(long)(b * 1024 + q) * 768 + h * 64 + n * 16 + lo] =
            __float2bfloat16(oacc[m][n][r] / lst[m][r]);
      }
}

// ===========================================================================
// helpers
// ===========================================================================
__global__ void detect_idx(const int* __restrict__ idx, int* __restrict__ flag)
{
  const int t = threadIdx.x;
  const int v = idx[2 * t + 1];
  const unsigned long long nz = __ballot(v != 0);
  if (t == 0) flag[0] = (nz == 0ull) ? 1 : 0;
}

__global__ __launch_bounds__(192)
void embed_kernel(const int* __restrict__ idx, const float* __restrict__ tok,
                  const float* __restrict__ pos, float* __restrict__ x,
                  const int* __restrict__ flag)
{
  const int row = blockIdx.x;
  const int t = row & 1023;
  const int id = flag[0] ? idx[2 * row] : idx[row];
  const int e = threadIdx.x * 4;
  const float4 a = *(const float4*)&tok[(long)id * 768 + e];
  const float4 p = *(const float4*)&pos[(long)t * 768 + e];
  float4 r; r.x = a.x + p.x; r.y = a.y + p.y; r.z = a.z + p.z; r.w = a.w + p.w;
  *(float4*)&x[(long)row * 768 + e] = r;
}

// wave-per-row LN body (4 rows per 256-thread block slice)
__device__ __forceinline__ void ln_rows(const float* __restrict__ x,
                                        const float* __restrict__ g,
                                        const float* __restrict__ bt,
                                        bf16* __restrict__ out,
                                        int row4, int tid)
{
  const int lane = tid & 63;
  const int row = row4 * 4 + (tid >> 6);
  const float* xr = x + (long)row * 768;
  f32x4 v[3];
  float s = 0.f, q = 0.f;
#pragma unroll
  for (int p = 0; p < 3; ++p) {
    v[p] = *(const f32x4*)&xr[lane * 4 + p * 256];
#pragma unroll
    for (int j = 0; j < 4; ++j) { s += v[p][j]; q += v[p][j] * v[p][j]; }
  }
#pragma unroll
  for (int o = 32; o > 0; o >>= 1) { s += __shfl_xor(s, o); q += __shfl_xor(q, o); }
  const float mu = s * (1.f / 768.f);
  const float var = q * (1.f / 768.f) - mu * mu;
  const float rs = rsqrtf(var + 1e-8f);
  bf16* orow = out + (long)row * 768;
#pragma unroll
  for (int p = 0; p < 3; ++p) {
    const int e = lane * 4 + p * 256;
    s16x4 pk;
#pragma unroll
    for (int j = 0; j < 4; ++j) {
      bf16 t = __float2bfloat16((v[p][j] - mu) * rs * g[e + j] + bt[e + j]);
      pk[j] = *(const short*)&t;
    }
    *(s16x4*)&orow[e] = pk;
  }
}

__global__ __launch_bounds__(256)
void ln_kernel(const float* __restrict__ x, const float* __restrict__ g,
               const float* __restrict__ bt, bf16* __restrict__ out)
{
  ln_rows(x, g, bt, out, blockIdx.x, threadIdx.x);
}

// 64x64 fp32->bf16 transpose tile
__device__ __forceinline__ void tile_tr64(const float* __restrict__ ip,
                                          bf16* __restrict__ op,
                                          int R, int Creal, int r0, int c0,
                                          int tid, float (*tile)[65])
{
  const int tx = tid & 63, ty = tid >> 6;
#pragma unroll
  for (int p = 0; p < 16; ++p) {
    const int r = p * 4 + ty;
    const int c = c0 + tx;
    tile[r][tx] = (c < Creal) ? ip[(long)(r0 + r) * Creal + c] : 0.f;
  }
  __syncthreads();
#pragma unroll
  for (int p = 0; p < 16; ++p) {
    const int cc = p * 4 + ty;
    op[(long)(c0 + cc) * R + r0 + tx] = __float2bfloat16(tile[tx][cc]);
  }
}

__global__ __launch_bounds__(256)
void transpose_conv(const float* __restrict__ in, bf16* __restrict__ out,
                    int R, int Creal)
{
  __shared__ float tile[64][65];
  tile_tr64(in, out, R, Creal, blockIdx.y * 64, blockIdx.x * 64, threadIdx.x, tile);
}

// per-layer weight repacks + FUSED LN1 (verified r16): blocks 0..1727 repack
// (qkv 432 | proj 144 | w1 576 | w2 576); 1728..2751 LN1.
__global__ __launch_bounds__(256)
void repack_layer(const float* __restrict__ wq, const float* __restrict__ wk,
                  const float* __restrict__ wv, const float* __restrict__ projw,
                  const float* __restrict__ w1, const float* __restrict__ w2,
                  const float* __restrict__ x, const float* __restrict__ ln1g,
                  const float* __restrict__ ln1b,
                  bf16* __restrict__ WqkvT, bf16* __restrict__ WprojT,
                  bf16* __restrict__ W1T, bf16* __restrict__ W2T,
                  bf16* __restrict__ xn)
{
  __shared__ float tile[64][65];
  const int tid = threadIdx.x;
  const int t = blockIdx.x;
  if (t < 432) {
    const int op_i = t / 144, r = t % 144;
    const int h = r / 12, ry = r % 12;
    const float* ip = (op_i == 0 ? wq : op_i == 1 ? wk : wv) + h * 49152;
    bf16* op = WqkvT + (long)op_i * 768 * 768 + (long)h * 64 * 768;
    tile_tr64(ip, op, 768, 64, ry * 64, 0, tid, tile);
  } else if (t < 576) {
    const int t2 = t - 432;
    const int r0 = (t2 / 12) * 64, c0 = (t2 % 12) * 64;
#pragma unroll
    for (int p = 0; p < 4; ++p) {
      const int row = r0 + p * 16 + (tid >> 4);
      const int col = c0 + (tid & 15) * 4;
      const float4 v = *(const float4*)&projw[(long)row * 768 + col];
      bf16 t0 = __float2bfloat16(v.x), t1 = __float2bfloat16(v.y);
      bf16 t2b = __float2bfloat16(v.z), t3 = __float2bfloat16(v.w);
      s16x4 pk;
      pk[0] = *(const short*)&t0; pk[1] = *(const short*)&t1;
      pk[2] = *(const short*)&t2b; pk[3] = *(const short*)&t3;
      *(s16x4*)&WprojT[(long)row * 768 + col] = pk;
    }
  } else if (t < 1152) {
    const int t3 = t - 576;
    tile_tr64(w1, W1T, 768, 3072, (t3 / 48) * 64, (t3 % 48) * 64, tid, tile);
  } else if (t < 1728) {
    const int t4 = t - 1152;
    tile_tr64(w2, W2T, 3072, 768, (t4 / 12) * 64, (t4 % 12) * 64, tid, tile);
  } else {
    ln_rows(x, ln1g, ln1b, xn, t - 1728, tid);   // fused LN1
  }
}

// ===========================================================================
extern "C" void kernel_launch(void* const* d_in, const int* in_sizes, int n_in,
                              void* d_out, int out_size, void* d_ws, size_t ws_size,
                              hipStream_t stream)
{
  (void)in_sizes; (void)n_in; (void)out_size; (void)ws_size;
  const int*   idx   = (const int*)d_in[0];
  const float* tok   = (const float*)d_in[1];
  const float* pos   = (const float*)d_in[2];
  const float* wq    = (const float*)d_in[3];
  const float* wk    = (const float*)d_in[4];
  const float* wv    = (const float*)d_in[5];
  const float* projw = (const float*)d_in[6];
  const float* projb = (const float*)d_in[7];
  const float* ln1g  = (const float*)d_in[8];
  const float* ln1b  = (const float*)d_in[9];
  const float* ln2g  = (const float*)d_in[10];
  const float* ln2b  = (const float*)d_in[11];
  const float* w1    = (const float*)d_in[12];
  const float* b1    = (const float*)d_in[13];
  const float* w2    = (const float*)d_in[14];
  const float* b2    = (const float*)d_in[15];
  const float* lnfg  = (const float*)d_in[16];
  const float* lnfb  = (const float*)d_in[17];
  const float* headw = (const float*)d_in[18];
  const float* headb = (const float*)d_in[19];
  float* out = (float*)d_out;

  char* ws = (char*)d_ws;
  size_t off = 0;
  auto alloc = [&](size_t bytes) -> void* {
    void* p = ws + off; off += (bytes + 255) & ~(size_t)255; return p;
  };
  int*   iflag  = (int*)  alloc(256);
  float* x      = (float*)alloc(4096ull * 768 * 4);
  bf16*  xn     = (bf16*) alloc(4096ull * 768 * 2);
  bf16*  qkvb   = (bf16*) alloc(4096ull * 2304 * 2);
  bf16*  ob     = (bf16*) alloc(4096ull * 768 * 2);
  bf16*  hb     = (bf16*) alloc(4096ull * 3072 * 2);
  bf16*  WqkvT  = (bf16*) alloc(2304ull * 768 * 2);
  bf16*  WprojT = (bf16*) alloc(768ull * 768 * 2);
  bf16*  W1T    = (bf16*) alloc(3072ull * 768 * 2);
  bf16*  W2T    = (bf16*) alloc(768ull * 3072 * 2);
  bf16*  headT  = (bf16*) alloc(50304ull * 768 * 2);

  detect_idx<<<1, 64, 0, stream>>>(idx, iflag);
  transpose_conv<<<dim3(786, 12), 256, 0, stream>>>(headw, headT, 768, 50257);
  embed_kernel<<<4096, 192, 0, stream>>>(idx, tok, pos, x, iflag);

  for (int l = 0; l < 12; ++l) {
    const size_t hOff = (size_t)l * 12 * 768 * 64;
    repack_layer<<<2752, 256, 0, stream>>>(wq + hOff, wk + hOff, wv + hOff,
                                           projw + (size_t)l * 768 * 768,
                                           w1 + (size_t)l * 768 * 3072,
                                           w2 + (size_t)l * 3072 * 768,
                                           x, ln1g + l * 768, ln1b + l * 768,
                                           WqkvT, WprojT, W1T, W2T, xn);

    gemm_bt256<EPI_BF16><<<dim3(18, 16), 512, 0, stream>>>(xn, WqkvT, nullptr, nullptr, qkvb, 768, 2304, 2304);
    attn_kernel<<<dim3(8, 48), 256, 0, stream>>>(qkvb, ob);
    gemm_bt64<EPI_RES><<<dim3(6, 64), 256, 0, stream>>>(ob, WprojT, projb + l * 768, x, nullptr, 4096, 768, 768, 768);
    ln_kernel<<<1024, 256, 0, stream>>>(x, ln2g + l * 768, ln2b + l * 768, xn);
    gemm_bt256<EPI_GELU><<<dim3(24, 16), 512, 0, stream>>>(xn, W1T, b1 + (size_t)l * 3072, nullptr, hb, 768, 3072, 3072);
    gemm_bt64<EPI_RES><<<dim3(6, 64), 256, 0, stream>>>(hb, W2T, b2 + l * 768, x, nullptr, 4096, 768, 3072, 768);
  }

  ln_kernel<<<1024, 256, 0, stream>>>(x, lnfg, lnfb, xn);
  gemm_bt256<EPI_HEAD><<<dim3(393, 16), 512, 0, stream>>>(xn, headT, headb, out, nullptr, 768, 50304, 50257);
}